// Round 2
// baseline (36.006 us; speedup 1.0000x reference)
//
#include <hip/hip_runtime.h>

#define NB 2048
#define NC 512
#define ND 256
#define VIG 0.75f
#define CHK 64
#define NCHK (ND / CHK)

__device__ __forceinline__ void load_lds16(const float* g, float* l) {
  __builtin_amdgcn_global_load_lds((const __attribute__((address_space(1))) void*)g,
                                   (__attribute__((address_space(3))) void*)l,
                                   16, 0, 0);
}

// Block: 16 rows x 64 cols. 256 threads = 4 waves; wave w owns rows [bm0+4w, +4),
// lane = column. cat tile staged to LDS (double-buffered, XOR-swizzled); x read
// via wave-uniform loads (scalar path). Grid 1024 blocks = 4 blocks/CU.
__global__ __launch_bounds__(256, 4) void fuzzy_main(const float* __restrict__ x,
                                                     const float* __restrict__ cat,
                                                     float* __restrict__ out) {
  __shared__ float cs[2][64 * CHK];  // [buf][col*64 + swizzled k] : 32 KiB
  __shared__ float part[16][4];
  __shared__ float rs[16];

  const int t = threadIdx.x;
  const int lane = t & 63;
  const int w = t >> 6;
  const int cn0 = blockIdx.x * 64;
  const int bm0 = blockIdx.y * 16;

  // staging: thread t covers LDS bytes r*4096 + t*16 (r = 0..3 per chunk).
  // LDS dword d of col c holds global k = d ^ ((c&7)<<2)  (16B-granule XOR swizzle)
  const int sc = t >> 4;                                // col sub-index (+ r*16)
  const int ksrc = ((t & 15) ^ ((t >> 4) & 7)) << 2;    // pre-swizzled float offset

  // stage chunk 0 -> cs[0]
#pragma unroll
  for (int r = 0; r < 4; ++r)
    load_lds16(cat + (size_t)(cn0 + r * 16 + sc) * ND + ksrc,
               &cs[0][r * 1024 + w * 256]);

  // row sums — summation order identical to the round-1 kernel (bit-exact pass)
  if (t < 64) {
    const int r = t >> 2, seg = t & 3;
    const float4* xr =
        reinterpret_cast<const float4*>(x + (size_t)(bm0 + r) * ND + seg * 64);
    float s = 0.f;
#pragma unroll
    for (int i = 0; i < 16; ++i) {
      float4 v = xr[i];
      s += v.x + v.y + v.z + v.w;
    }
    part[r][seg] = s;
  }
  __syncthreads();  // stage-0 drained (vmcnt) + part visible
  if (t < 16) rs[t] = part[t][0] + part[t][1] + part[t][2] + part[t][3];

  const int row0 = __builtin_amdgcn_readfirstlane(bm0 + w * 4);
  const float* xp = x + (size_t)row0 * ND;
  const int csw = (lane & 7) << 2;

  float acc0 = 0.f, acc1 = 0.f, acc2 = 0.f, acc3 = 0.f;

#pragma unroll
  for (int ch = 0; ch < NCHK; ++ch) {
    if (ch + 1 < NCHK) {
#pragma unroll
      for (int r = 0; r < 4; ++r)
        load_lds16(cat + (size_t)(cn0 + r * 16 + sc) * ND + (ch + 1) * CHK + ksrc,
                   &cs[(ch + 1) & 1][r * 1024 + w * 256]);
    }
    const float* cb = &cs[ch & 1][lane * 64];
    const float* xq0 = xp + ch * CHK;
    const float* xq1 = xq0 + ND;
    const float* xq2 = xq1 + ND;
    const float* xq3 = xq2 + ND;
#pragma unroll 4
    for (int kk = 0; kk < CHK; kk += 4) {
      const float4 cv = *reinterpret_cast<const float4*>(cb + (kk ^ csw));
      const float4 a0 = *reinterpret_cast<const float4*>(xq0 + kk);
      const float4 a1 = *reinterpret_cast<const float4*>(xq1 + kk);
      const float4 a2 = *reinterpret_cast<const float4*>(xq2 + kk);
      const float4 a3 = *reinterpret_cast<const float4*>(xq3 + kk);
      acc0 += fminf(a0.x, cv.x); acc0 += fminf(a0.y, cv.y);
      acc0 += fminf(a0.z, cv.z); acc0 += fminf(a0.w, cv.w);
      acc1 += fminf(a1.x, cv.x); acc1 += fminf(a1.y, cv.y);
      acc1 += fminf(a1.z, cv.z); acc1 += fminf(a1.w, cv.w);
      acc2 += fminf(a2.x, cv.x); acc2 += fminf(a2.y, cv.y);
      acc2 += fminf(a2.z, cv.z); acc2 += fminf(a2.w, cv.w);
      acc3 += fminf(a3.x, cv.x); acc3 += fminf(a3.y, cv.y);
      acc3 += fminf(a3.z, cv.z); acc3 += fminf(a3.w, cv.w);
    }
    __syncthreads();  // drains this iter's staging; next iter computes from it
  }

  const float r0 = rs[w * 4 + 0], r1 = rs[w * 4 + 1];
  const float r2 = rs[w * 4 + 2], r3 = rs[w * 4 + 3];
  float v0 = acc0 / r0, v1 = acc1 / r1, v2 = acc2 / r2, v3 = acc3 / r3;
  v0 = (v0 >= VIG) ? v0 : 0.f;
  v1 = (v1 >= VIG) ? v1 : 0.f;
  v2 = (v2 >= VIG) ? v2 : 0.f;
  v3 = (v3 >= VIG) ? v3 : 0.f;
  float* o = out + (size_t)row0 * NC + cn0 + lane;
  o[0] = v0;
  o[NC] = v1;
  o[2 * NC] = v2;
  o[3 * NC] = v3;
}

__global__ __launch_bounds__(256) void fuzzy_argmax(const float* __restrict__ scores,
                                                    float* __restrict__ outIdx) {
  const int wv = threadIdx.x >> 6;
  const int lane = threadIdx.x & 63;
  const int row = blockIdx.x * 4 + wv;
  const float* s = scores + (size_t)row * NC;

  float best = -1.0f;
  int bidx = 0;
#pragma unroll
  for (int half = 0; half < 2; ++half) {
    const int j0 = half * 256 + lane * 4;
    float4 v = *reinterpret_cast<const float4*>(s + j0);
    float vv[4] = {v.x, v.y, v.z, v.w};
#pragma unroll
    for (int j = 0; j < 4; ++j) {
      if (vv[j] > best) {  // strict > keeps lowest index (ascending scan)
        best = vv[j];
        bidx = j0 + j;
      }
    }
  }
#pragma unroll
  for (int off = 32; off > 0; off >>= 1) {
    float ob = __shfl_xor(best, off, 64);
    int oi = __shfl_xor(bidx, off, 64);
    if (ob > best || (ob == best && oi < bidx)) {
      best = ob;
      bidx = oi;
    }
  }
  if (lane == 0) outIdx[row] = (float)bidx;
}

extern "C" void kernel_launch(void* const* d_in, const int* in_sizes, int n_in,
                              void* d_out, int out_size, void* d_ws, size_t ws_size,
                              hipStream_t stream) {
  const float* x = (const float*)d_in[0];
  const float* cat = (const float*)d_in[1];
  float* out = (float*)d_out;

  fuzzy_main<<<dim3(NC / 64, NB / 16), 256, 0, stream>>>(x, cat, out);
  fuzzy_argmax<<<NB / 4, 256, 0, stream>>>(out, out + (size_t)NB * NC);
}

// Round 3
// 34.053 us; speedup vs baseline: 1.0573x; 1.0573x over previous
//
#include <hip/hip_runtime.h>

#define NB 2048
#define NC 512
#define ND 256
#define VIG 0.75f
#define CK 16
#define NCHK (ND / CK)  // 16 chunks

__device__ __forceinline__ void load_lds16(const float* g, float* l) {
  __builtin_amdgcn_global_load_lds((const __attribute__((address_space(1))) void*)g,
                                   (__attribute__((address_space(3))) void*)l,
                                   16, 0, 0);
}

// One block = 4 rows x 512 cols. 4 waves; wave w owns cols [w*128, w*128+128);
// lane owns cols c0 = w*128+lane and c0+64. cat chunk (512 cols x 16 k) staged
// to LDS double-buffered via global_load_lds, granule-swizzled: LDS granule
// G = col*4 + (g ^ ((col>>1)&3)) holds global k-granule g of col. x reads are
// block-uniform -> scalar loads. Scores + fused argmax written at the end.
__global__ __launch_bounds__(256, 2) void fuzzy_fused(const float* __restrict__ x,
                                                      const float* __restrict__ cat,
                                                      float* __restrict__ out) {
  __shared__ float cs[2][512 * CK];  // 2 x 32 KiB
  __shared__ float part[4][4];
  __shared__ float rs[4];
  __shared__ float red[4][4][2];  // [row][wave][val, idx]

  const int t = threadIdx.x;
  const int lane = t & 63;
  const int w = t >> 6;
  const int bm0 = blockIdx.x * 4;

  // ---- per-lane staging source offsets (inverse-swizzled global source) ----
  // wave w instr i covers LDS granules [w*512 + i*64, +64), lane -> +lane.
  // granule G: col = G>>2, stored global k-granule g = (G&3) ^ ((G>>3)&3).
  int soff[8];
#pragma unroll
  for (int i = 0; i < 8; ++i) {
    const int G = w * 512 + i * 64 + lane;
    const int col = G >> 2;
    const int g = (G & 3) ^ ((G >> 3) & 3);
    soff[i] = col * ND + g * 4;  // float offset; + ck*CK per chunk
  }

#define STAGE(buf, ck)                                              \
  do {                                                              \
    _Pragma("unroll") for (int i = 0; i < 8; ++i)                   \
        load_lds16(cat + soff[i] + (ck) * CK,                       \
                   &cs[buf][w * 2048 + i * 256]);                   \
  } while (0)

  STAGE(0, 0);

  // ---- row sums: summation order identical to round-1 (bit-exact) ----
  if (t < 16) {
    const int r = t >> 2, seg = t & 3;
    const float4* xr =
        reinterpret_cast<const float4*>(x + (size_t)(bm0 + r) * ND + seg * 64);
    float s = 0.f;
#pragma unroll
    for (int i = 0; i < 16; ++i) {
      float4 v = xr[i];
      s += v.x + v.y + v.z + v.w;
    }
    part[r][seg] = s;
  }
  __syncthreads();  // stage-0 drained (compiler vmcnt) + part visible
  if (t < 4) rs[t] = part[t][0] + part[t][1] + part[t][2] + part[t][3];

  const int c0 = w * 128 + lane;  // second col = c0 + 64, same swizzle key
  const int s0 = (c0 >> 1) & 3;
  const float* xr0 = x + (size_t)bm0 * ND;  // block-uniform -> scalar loads

  float a00 = 0.f, a01 = 0.f, a10 = 0.f, a11 = 0.f;
  float a20 = 0.f, a21 = 0.f, a30 = 0.f, a31 = 0.f;

#pragma unroll 1
  for (int ck = 0; ck < NCHK; ++ck) {
    if (ck + 1 < NCHK) {
      if ((ck & 1) == 0) STAGE(1, ck + 1); else STAGE(0, ck + 1);
    }
    const float* cb = &cs[ck & 1][0];
    const float* xq = xr0 + ck * CK;
#pragma unroll
    for (int k2 = 0; k2 < 4; ++k2) {
      const int sw = ((k2 ^ s0) << 2);
      const float4 cv0 = *reinterpret_cast<const float4*>(&cb[c0 * 16 + sw]);
      const float4 cv1 =
          *reinterpret_cast<const float4*>(&cb[(c0 + 64) * 16 + sw]);
      const float4 x0 = *reinterpret_cast<const float4*>(xq + k2 * 4);
      const float4 x1 = *reinterpret_cast<const float4*>(xq + ND + k2 * 4);
      const float4 x2 = *reinterpret_cast<const float4*>(xq + 2 * ND + k2 * 4);
      const float4 x3 = *reinterpret_cast<const float4*>(xq + 3 * ND + k2 * 4);
      a00 += fminf(x0.x, cv0.x); a00 += fminf(x0.y, cv0.y);
      a00 += fminf(x0.z, cv0.z); a00 += fminf(x0.w, cv0.w);
      a01 += fminf(x0.x, cv1.x); a01 += fminf(x0.y, cv1.y);
      a01 += fminf(x0.z, cv1.z); a01 += fminf(x0.w, cv1.w);
      a10 += fminf(x1.x, cv0.x); a10 += fminf(x1.y, cv0.y);
      a10 += fminf(x1.z, cv0.z); a10 += fminf(x1.w, cv0.w);
      a11 += fminf(x1.x, cv1.x); a11 += fminf(x1.y, cv1.y);
      a11 += fminf(x1.z, cv1.z); a11 += fminf(x1.w, cv1.w);
      a20 += fminf(x2.x, cv0.x); a20 += fminf(x2.y, cv0.y);
      a20 += fminf(x2.z, cv0.z); a20 += fminf(x2.w, cv0.w);
      a21 += fminf(x2.x, cv1.x); a21 += fminf(x2.y, cv1.y);
      a21 += fminf(x2.z, cv1.z); a21 += fminf(x2.w, cv1.w);
      a30 += fminf(x3.x, cv0.x); a30 += fminf(x3.y, cv0.y);
      a30 += fminf(x3.z, cv0.z); a30 += fminf(x3.w, cv0.w);
      a31 += fminf(x3.x, cv1.x); a31 += fminf(x3.y, cv1.y);
      a31 += fminf(x3.z, cv1.z); a31 += fminf(x3.w, cv1.w);
    }
    __syncthreads();
  }

  // ---- epilogue: divide, threshold, store scores, fused argmax ----
  const float r0 = rs[0], r1 = rs[1], r2 = rs[2], r3 = rs[3];
  float v00 = a00 / r0, v01 = a01 / r0;
  float v10 = a10 / r1, v11 = a11 / r1;
  float v20 = a20 / r2, v21 = a21 / r2;
  float v30 = a30 / r3, v31 = a31 / r3;
  v00 = (v00 >= VIG) ? v00 : 0.f;  v01 = (v01 >= VIG) ? v01 : 0.f;
  v10 = (v10 >= VIG) ? v10 : 0.f;  v11 = (v11 >= VIG) ? v11 : 0.f;
  v20 = (v20 >= VIG) ? v20 : 0.f;  v21 = (v21 >= VIG) ? v21 : 0.f;
  v30 = (v30 >= VIG) ? v30 : 0.f;  v31 = (v31 >= VIG) ? v31 : 0.f;

  float* o0 = out + (size_t)bm0 * NC + c0;
  o0[0] = v00;            o0[64] = v01;
  o0[NC] = v10;           o0[NC + 64] = v11;
  o0[2 * NC] = v20;       o0[2 * NC + 64] = v21;
  o0[3 * NC] = v30;       o0[3 * NC + 64] = v31;

  // per-row wave-level argmax (lane cols c0 < c0+64; strict > keeps low col)
#pragma unroll
  for (int r = 0; r < 4; ++r) {
    float bv; float v0, v1;
    if (r == 0) { v0 = v00; v1 = v01; }
    else if (r == 1) { v0 = v10; v1 = v11; }
    else if (r == 2) { v0 = v20; v1 = v21; }
    else { v0 = v30; v1 = v31; }
    int bi = c0;
    bv = v0;
    if (v1 > bv) { bv = v1; bi = c0 + 64; }
#pragma unroll
    for (int off = 32; off > 0; off >>= 1) {
      float ob = __shfl_xor(bv, off, 64);
      int oi = __shfl_xor(bi, off, 64);
      if (ob > bv || (ob == bv && oi < bi)) { bv = ob; bi = oi; }
    }
    if (lane == 0) { red[r][w][0] = bv; red[r][w][1] = (float)bi; }
  }
  __syncthreads();
  if (t < 4) {
    float bv = red[t][0][0];
    float bi = red[t][0][1];
#pragma unroll
    for (int w2 = 1; w2 < 4; ++w2) {
      float ov = red[t][w2][0], oi = red[t][w2][1];
      if (ov > bv) { bv = ov; bi = oi; }  // strict >: lower wave = lower cols
    }
    out[(size_t)NB * NC + bm0 + t] = bi;
  }
#undef STAGE
}

extern "C" void kernel_launch(void* const* d_in, const int* in_sizes, int n_in,
                              void* d_out, int out_size, void* d_ws, size_t ws_size,
                              hipStream_t stream) {
  const float* x = (const float*)d_in[0];
  const float* cat = (const float*)d_in[1];
  float* out = (float*)d_out;

  fuzzy_fused<<<NB / 4, 256, 0, stream>>>(x, cat, out);
}